// Round 1
// baseline (709.682 us; speedup 1.0000x reference)
//
#include <hip/hip_runtime.h>
#include <math.h>

typedef unsigned short u16;
typedef unsigned int u32;
typedef __attribute__((ext_vector_type(4))) float f32x4;
typedef __attribute__((ext_vector_type(8))) short short8;
typedef __attribute__((ext_vector_type(4))) unsigned short u16x4;

#define B_DIM 2
#define L_SEQ 4096
#define E_DIM 512
#define NH 8
#define HD 64
#define HID_DIM 2048
#define BL (B_DIM * L_SEQ)

__device__ __forceinline__ float bf2f(u16 u) {
    union { u32 i; float f; } v; v.i = ((u32)u) << 16; return v.f;
}
__device__ __forceinline__ u16 f2bf(float f) {
    union { float f; u32 i; } v; v.f = f;
    u32 r = v.i + 0x7fffu + ((v.i >> 16) & 1u);
    return (u16)(r >> 16);
}

#define GLOAD_LDS16(gp, lp) __builtin_amdgcn_global_load_lds( \
    (const __attribute__((address_space(1))) void*)(gp),      \
    (__attribute__((address_space(3))) void*)(lp), 16, 0, 0)

// ---------------- weight convert + transpose: f32 [Kd][Nd] -> bf16 [Nd][Kd] ----------------
__global__ __launch_bounds__(256) void wconv_t(const float* __restrict__ in,
                                               u16* __restrict__ out, int Kd, int Nd) {
    int idx = blockIdx.x * 256 + threadIdx.x;
    if (idx >= Kd * Nd) return;
    int k = idx / Nd, n = idx - k * Nd;
    out[(size_t)n * Kd + k] = f2bf(in[idx]);
}

// ---------------- LayerNorm: f32 [rows][512] -> bf16 [rows][512], wave per row ----------------
__global__ __launch_bounds__(256) void ln_kernel(const float* __restrict__ x,
                                                 const float* __restrict__ g,
                                                 const float* __restrict__ b,
                                                 u16* __restrict__ out) {
    const int row = blockIdx.x * 4 + (threadIdx.x >> 6);
    const int lane = threadIdx.x & 63;
    const float4* xr = (const float4*)(x + (size_t)row * E_DIM);
    const float4 v0 = xr[lane];
    const float4 v1 = xr[lane + 64];
    float s  = v0.x + v0.y + v0.z + v0.w + v1.x + v1.y + v1.z + v1.w;
    float s2 = v0.x*v0.x + v0.y*v0.y + v0.z*v0.z + v0.w*v0.w
             + v1.x*v1.x + v1.y*v1.y + v1.z*v1.z + v1.w*v1.w;
#pragma unroll
    for (int off = 32; off > 0; off >>= 1) {
        s  += __shfl_xor(s, off);
        s2 += __shfl_xor(s2, off);
    }
    const float mu = s * (1.f / E_DIM);
    const float rs = rsqrtf(s2 * (1.f / E_DIM) - mu * mu + 1e-5f);
    const float4 g0 = ((const float4*)g)[lane], g1 = ((const float4*)g)[lane + 64];
    const float4 b0 = ((const float4*)b)[lane], b1 = ((const float4*)b)[lane + 64];
    u16x4 o0, o1;
    o0.x = f2bf((v0.x - mu) * rs * g0.x + b0.x);
    o0.y = f2bf((v0.y - mu) * rs * g0.y + b0.y);
    o0.z = f2bf((v0.z - mu) * rs * g0.z + b0.z);
    o0.w = f2bf((v0.w - mu) * rs * g0.w + b0.w);
    o1.x = f2bf((v1.x - mu) * rs * g1.x + b1.x);
    o1.y = f2bf((v1.y - mu) * rs * g1.y + b1.y);
    o1.z = f2bf((v1.z - mu) * rs * g1.z + b1.z);
    o1.w = f2bf((v1.w - mu) * rs * g1.w + b1.w);
    u16x4* orow = (u16x4*)(out + (size_t)row * E_DIM);
    orow[lane] = o0;
    orow[lane + 64] = o1;
}

// ---------------- GEMM: C[M][N] = A[M][K](bf16) @ Bt[N][K](bf16) + bias (+gelu) (+res) -------
// 128x128 tile, BK=32, 4 waves (2x2), each wave 4x4 fragments of mfma_f32_16x16x32_bf16.
template<bool RES, bool GELU, bool OUTBF>
__global__ __launch_bounds__(256) void gemm_bt(const u16* __restrict__ A,
                                               const u16* __restrict__ Bt,
                                               const float* __restrict__ bias,
                                               const float* __restrict__ res,
                                               void* __restrict__ Cp,
                                               int M, int N, int K) {
    __shared__ u16 lds_a[128 * 32];
    __shared__ u16 lds_b[128 * 32];
    const int tid = threadIdx.x;
    const int wave = tid >> 6;
    const int lane = tid & 63;
    const int wr = wave >> 1, wc = wave & 1;
    const int bm = blockIdx.y * 128, bn = blockIdx.x * 128;

    f32x4 acc[4][4];
#pragma unroll
    for (int m = 0; m < 4; ++m)
#pragma unroll
        for (int n = 0; n < 4; ++n) acc[m][n] = 0.f;

    const int r_in_wave = lane >> 2;       // 0..15
    const int kc = (lane & 3) * 8;         // k element offset, lane-linear with lds dest
    const u16* gA = A + (size_t)(bm + wave * 32 + r_in_wave) * K + kc;
    const u16* gB = Bt + (size_t)(bn + wave * 32 + r_in_wave) * K + kc;
    u16* la = &lds_a[(wave * 32) * 32];
    u16* lb = &lds_b[(wave * 32) * 32];

    const int frow = lane & 15;
    const int fk = (lane >> 4) * 8;

    for (int k0 = 0; k0 < K; k0 += 32) {
        GLOAD_LDS16(gA + k0, la);
        GLOAD_LDS16(gA + k0 + (size_t)16 * K, la + 16 * 32);
        GLOAD_LDS16(gB + k0, lb);
        GLOAD_LDS16(gB + k0 + (size_t)16 * K, lb + 16 * 32);
        __syncthreads();   // drains vmcnt -> LDS tile ready

        short8 af[4], bfr[4];
#pragma unroll
        for (int m = 0; m < 4; ++m)
            af[m] = *(const short8*)&lds_a[(wr * 64 + m * 16 + frow) * 32 + fk];
#pragma unroll
        for (int n = 0; n < 4; ++n)
            bfr[n] = *(const short8*)&lds_b[(wc * 64 + n * 16 + frow) * 32 + fk];
#pragma unroll
        for (int m = 0; m < 4; ++m)
#pragma unroll
            for (int n = 0; n < 4; ++n)
                acc[m][n] = __builtin_amdgcn_mfma_f32_16x16x32_bf16(af[m], bfr[n], acc[m][n], 0, 0, 0);
        __syncthreads();   // all reads done before restage
    }

    const int ccol = lane & 15;
    const int crow = (lane >> 4) * 4;
#pragma unroll
    for (int n = 0; n < 4; ++n) {
        const int gc = bn + wc * 64 + n * 16 + ccol;
        const float bi = bias[gc];
#pragma unroll
        for (int m = 0; m < 4; ++m) {
            const int gr0 = bm + wr * 64 + m * 16 + crow;
#pragma unroll
            for (int j = 0; j < 4; ++j) {
                float v = acc[m][n][j] + bi;
                if (GELU) v = 0.5f * v * (1.f + erff(v * 0.70710678118f));
                const size_t idx = (size_t)(gr0 + j) * N + gc;
                if (RES) v += res[idx];
                if (OUTBF) ((u16*)Cp)[idx] = f2bf(v);
                else       ((float*)Cp)[idx] = v;
            }
        }
    }
}

// ---------------- dilated attention: one wave per (b,h,q-row), lane = head dim -------------
// allowed keys: j = i - 2t, t = 0..min(128, i/2)  (causal, window 256, dilation 2)
__global__ __launch_bounds__(256) void attn_kernel(const u16* __restrict__ qkv,
                                                   u16* __restrict__ o) {
    const int gid = blockIdx.x * 4 + (threadIdx.x >> 6);   // (b*NH + h)*L + i
    const int lane = threadIdx.x & 63;
    const int i = gid & (L_SEQ - 1);
    const int h = (gid >> 12) & (NH - 1);
    const int b = gid >> 15;

    const u16* base = qkv + (size_t)(b * L_SEQ) * (3 * E_DIM) + h * HD;
    const float qd = bf2f(base[(size_t)i * (3 * E_DIM) + lane]);

    float mx = -3.4e38f, l = 0.f, acc = 0.f;
    const int t_end = min(128, i >> 1);
    for (int t = 0; t <= t_end; ++t) {
        const int j = i - 2 * t;
        const u16* krow = base + (size_t)j * (3 * E_DIM) + E_DIM;   // k section
        float p = qd * bf2f(krow[lane]);
#pragma unroll
        for (int off = 32; off > 0; off >>= 1) p += __shfl_xor(p, off);
        const float s = p * 0.125f;                                  // 1/sqrt(64)
        const float mn = fmaxf(mx, s);
        const float sc = __expf(mx - mn);
        const float pe = __expf(s - mn);
        l = l * sc + pe;
        acc = acc * sc + pe * bf2f(krow[lane + E_DIM]);              // v section
        mx = mn;
    }
    o[(size_t)(b * L_SEQ + i) * E_DIM + h * HD + lane] = f2bf(acc / l);
}

// --------------------------------------------------------------------------------------------
extern "C" void kernel_launch(void* const* d_in, const int* in_sizes, int n_in,
                              void* d_out, int out_size, void* d_ws, size_t ws_size,
                              hipStream_t stream) {
    const float* x    = (const float*)d_in[0];
    const float* ln1g = (const float*)d_in[1];
    const float* ln1b = (const float*)d_in[2];
    const float* qkvw = (const float*)d_in[3];
    const float* qkvb = (const float*)d_in[4];
    const float* outw = (const float*)d_in[5];
    const float* outb = (const float*)d_in[6];
    const float* ln2g = (const float*)d_in[7];
    const float* ln2b = (const float*)d_in[8];
    const float* w1   = (const float*)d_in[9];
    const float* b1   = (const float*)d_in[10];
    const float* w2   = (const float*)d_in[11];
    const float* b2   = (const float*)d_in[12];
    float* outp = (float*)d_out;

    char* ws = (char*)d_ws;
    size_t off = 0;
    auto alloc = [&](size_t bytes) {
        void* p = ws + off;
        off += (bytes + 255) & ~(size_t)255;
        return p;
    };
    u16*   hbuf  = (u16*)  alloc((size_t)BL * E_DIM * 2);
    u16*   qkvB  = (u16*)  alloc((size_t)BL * 3 * E_DIM * 2);
    u16*   obuf  = (u16*)  alloc((size_t)BL * E_DIM * 2);
    float* x2    = (float*)alloc((size_t)BL * E_DIM * 4);
    u16*   h2    = (u16*)  alloc((size_t)BL * E_DIM * 2);
    u16*   g1    = (u16*)  alloc((size_t)BL * HID_DIM * 2);
    u16*   wqkvT = (u16*)  alloc((size_t)3 * E_DIM * E_DIM * 2);
    u16*   woutT = (u16*)  alloc((size_t)E_DIM * E_DIM * 2);
    u16*   w1T   = (u16*)  alloc((size_t)HID_DIM * E_DIM * 2);
    u16*   w2T   = (u16*)  alloc((size_t)E_DIM * HID_DIM * 2);

    wconv_t<<<(E_DIM * 3 * E_DIM + 255) / 256, 256, 0, stream>>>(qkvw, wqkvT, E_DIM, 3 * E_DIM);
    wconv_t<<<(E_DIM * E_DIM + 255) / 256, 256, 0, stream>>>(outw, woutT, E_DIM, E_DIM);
    wconv_t<<<(E_DIM * HID_DIM + 255) / 256, 256, 0, stream>>>(w1, w1T, E_DIM, HID_DIM);
    wconv_t<<<(HID_DIM * E_DIM + 255) / 256, 256, 0, stream>>>(w2, w2T, HID_DIM, E_DIM);

    ln_kernel<<<BL / 4, 256, 0, stream>>>(x, ln1g, ln1b, hbuf);
    gemm_bt<false, false, true><<<dim3((3 * E_DIM) / 128, BL / 128), 256, 0, stream>>>(
        hbuf, wqkvT, qkvb, nullptr, qkvB, BL, 3 * E_DIM, E_DIM);
    attn_kernel<<<(B_DIM * NH * L_SEQ) / 4, 256, 0, stream>>>(qkvB, obuf);
    gemm_bt<true, false, false><<<dim3(E_DIM / 128, BL / 128), 256, 0, stream>>>(
        obuf, woutT, outb, x, x2, BL, E_DIM, E_DIM);
    ln_kernel<<<BL / 4, 256, 0, stream>>>(x2, ln2g, ln2b, h2);
    gemm_bt<false, true, true><<<dim3(HID_DIM / 128, BL / 128), 256, 0, stream>>>(
        h2, w1T, b1, nullptr, g1, BL, HID_DIM, E_DIM);
    gemm_bt<true, false, false><<<dim3(E_DIM / 128, BL / 128), 256, 0, stream>>>(
        g1, w2T, b2, x2, outp, BL, E_DIM, HID_DIM);
}

// Round 2
// 199.416 us; speedup vs baseline: 3.5588x; 3.5588x over previous
//
#include <hip/hip_runtime.h>
#include <math.h>

typedef unsigned short u16;
typedef unsigned int u32;
typedef __attribute__((ext_vector_type(4))) float f32x4;
typedef __attribute__((ext_vector_type(8))) short short8;
typedef __attribute__((ext_vector_type(4))) unsigned short u16x4;

#define B_DIM 2
#define L_SEQ 4096
#define E_DIM 512
#define NH 8
#define HD 64
#define HID_DIM 2048
#define BL (B_DIM * L_SEQ)

__device__ __forceinline__ float bf2f(u16 u) {
    union { u32 i; float f; } v; v.i = ((u32)u) << 16; return v.f;
}
__device__ __forceinline__ u16 f2bf(float f) {
    union { float f; u32 i; } v; v.f = f;
    u32 r = v.i + 0x7fffu + ((v.i >> 16) & 1u);
    return (u16)(r >> 16);
}

#define GLOAD_LDS16(gp, lp) __builtin_amdgcn_global_load_lds( \
    (const __attribute__((address_space(1))) void*)(gp),      \
    (__attribute__((address_space(3))) void*)(lp), 16, 0, 0)

// ---------------- weight convert + transpose: f32 [Kd][Nd] -> bf16 [Nd][Kd] ----------------
__global__ __launch_bounds__(256) void wconv_t(const float* __restrict__ in,
                                               u16* __restrict__ out, int Kd, int Nd) {
    int idx = blockIdx.x * 256 + threadIdx.x;
    if (idx >= Kd * Nd) return;
    int k = idx / Nd, n = idx - k * Nd;
    out[(size_t)n * Kd + k] = f2bf(in[idx]);
}

// ---------------- LayerNorm: f32 [rows][512] -> bf16 [rows][512], wave per row ----------------
__global__ __launch_bounds__(256) void ln_kernel(const float* __restrict__ x,
                                                 const float* __restrict__ g,
                                                 const float* __restrict__ b,
                                                 u16* __restrict__ out) {
    const int row = blockIdx.x * 4 + (threadIdx.x >> 6);
    const int lane = threadIdx.x & 63;
    const float4* xr = (const float4*)(x + (size_t)row * E_DIM);
    const float4 v0 = xr[lane];
    const float4 v1 = xr[lane + 64];
    float s  = v0.x + v0.y + v0.z + v0.w + v1.x + v1.y + v1.z + v1.w;
    float s2 = v0.x*v0.x + v0.y*v0.y + v0.z*v0.z + v0.w*v0.w
             + v1.x*v1.x + v1.y*v1.y + v1.z*v1.z + v1.w*v1.w;
#pragma unroll
    for (int off = 32; off > 0; off >>= 1) {
        s  += __shfl_xor(s, off);
        s2 += __shfl_xor(s2, off);
    }
    const float mu = s * (1.f / E_DIM);
    const float rs = rsqrtf(s2 * (1.f / E_DIM) - mu * mu + 1e-5f);
    const float4 g0 = ((const float4*)g)[lane], g1 = ((const float4*)g)[lane + 64];
    const float4 b0 = ((const float4*)b)[lane], b1 = ((const float4*)b)[lane + 64];
    u16x4 o0, o1;
    o0.x = f2bf((v0.x - mu) * rs * g0.x + b0.x);
    o0.y = f2bf((v0.y - mu) * rs * g0.y + b0.y);
    o0.z = f2bf((v0.z - mu) * rs * g0.z + b0.z);
    o0.w = f2bf((v0.w - mu) * rs * g0.w + b0.w);
    o1.x = f2bf((v1.x - mu) * rs * g1.x + b1.x);
    o1.y = f2bf((v1.y - mu) * rs * g1.y + b1.y);
    o1.z = f2bf((v1.z - mu) * rs * g1.z + b1.z);
    o1.w = f2bf((v1.w - mu) * rs * g1.w + b1.w);
    u16x4* orow = (u16x4*)(out + (size_t)row * E_DIM);
    orow[lane] = o0;
    orow[lane + 64] = o1;
}

// ---------------- GEMM: C[M][N] = A[M][K](bf16) @ Bt[N][K](bf16) + bias (+gelu) (+res) -------
template<bool RES, bool GELU, bool OUTBF>
__global__ __launch_bounds__(256) void gemm_bt(const u16* __restrict__ A,
                                               const u16* __restrict__ Bt,
                                               const float* __restrict__ bias,
                                               const float* __restrict__ res,
                                               void* __restrict__ Cp,
                                               int M, int N, int K) {
    __shared__ u16 lds_a[128 * 32];
    __shared__ u16 lds_b[128 * 32];
    const int tid = threadIdx.x;
    const int wave = tid >> 6;
    const int lane = tid & 63;
    const int wr = wave >> 1, wc = wave & 1;
    const int bm = blockIdx.y * 128, bn = blockIdx.x * 128;

    f32x4 acc[4][4];
#pragma unroll
    for (int m = 0; m < 4; ++m)
#pragma unroll
        for (int n = 0; n < 4; ++n) acc[m][n] = 0.f;

    const int r_in_wave = lane >> 2;
    const int kc = (lane & 3) * 8;
    const u16* gA = A + (size_t)(bm + wave * 32 + r_in_wave) * K + kc;
    const u16* gB = Bt + (size_t)(bn + wave * 32 + r_in_wave) * K + kc;
    u16* la = &lds_a[(wave * 32) * 32];
    u16* lb = &lds_b[(wave * 32) * 32];

    const int frow = lane & 15;
    const int fk = (lane >> 4) * 8;

    for (int k0 = 0; k0 < K; k0 += 32) {
        GLOAD_LDS16(gA + k0, la);
        GLOAD_LDS16(gA + k0 + (size_t)16 * K, la + 16 * 32);
        GLOAD_LDS16(gB + k0, lb);
        GLOAD_LDS16(gB + k0 + (size_t)16 * K, lb + 16 * 32);
        __syncthreads();

        short8 af[4], bfr[4];
#pragma unroll
        for (int m = 0; m < 4; ++m)
            af[m] = *(const short8*)&lds_a[(wr * 64 + m * 16 + frow) * 32 + fk];
#pragma unroll
        for (int n = 0; n < 4; ++n)
            bfr[n] = *(const short8*)&lds_b[(wc * 64 + n * 16 + frow) * 32 + fk];
#pragma unroll
        for (int m = 0; m < 4; ++m)
#pragma unroll
            for (int n = 0; n < 4; ++n)
                acc[m][n] = __builtin_amdgcn_mfma_f32_16x16x32_bf16(af[m], bfr[n], acc[m][n], 0, 0, 0);
        __syncthreads();
    }

    const int ccol = lane & 15;
    const int crow = (lane >> 4) * 4;
#pragma unroll
    for (int n = 0; n < 4; ++n) {
        const int gc = bn + wc * 64 + n * 16 + ccol;
        const float bi = bias[gc];
#pragma unroll
        for (int m = 0; m < 4; ++m) {
            const int gr0 = bm + wr * 64 + m * 16 + crow;
#pragma unroll
            for (int j = 0; j < 4; ++j) {
                float v = acc[m][n][j] + bi;
                if (GELU) v = 0.5f * v * (1.f + erff(v * 0.70710678118f));
                const size_t idx = (size_t)(gr0 + j) * N + gc;
                if (RES) v += res[idx];
                if (OUTBF) ((u16*)Cp)[idx] = f2bf(v);
                else       ((float*)Cp)[idx] = v;
            }
        }
    }
}

// ---------------- dilated attention via parity split -> dense sliding-window flash attn ------
// Subsequence (b,parity): length 2048; query qs attends keys ks with 0 <= qs-ks <= 128.
// Block: 4 waves, Q-tile 64 rows (wave w owns 16). KV-blocks of 32, 6 per tile.
// S^T = mfma(K_frag, Q_frag): lane holds S^T[k=16t+4g+j][q=lane&15] -> softmax lane-local in q.
// PV: O^T = mfma(Vt_frag, P_frag), rescale lane-local. K_lds XOR-granule-swizzled (T2/m173).
__global__ __launch_bounds__(256) void attn_mfma(const u16* __restrict__ qkv,
                                                 u16* __restrict__ o) {
    __shared__ u16 K_lds[32 * 64];
    __shared__ u16 V_lds[32 * 64];
    const int tid = threadIdx.x;
    const int w = tid >> 6, lane = tid & 63;
    const int g = lane >> 4, q = lane & 15;
    const int qt = blockIdx.x, bph = blockIdx.y;
    const int b = bph >> 4, p = (bph >> 3) & 1, h = bph & 7;
    const int q0 = qt * 64;

    const size_t rowstride = 3 * E_DIM;
    const u16* qbase = qkv + (size_t)b * L_SEQ * rowstride + h * HD;

    const int qmin = q0 + w * 16, qmax = qmin + 15;
    const int qs_lane = qmin + q;
    const int qi = 2 * qs_lane + p;

    short8 qfrag[2];
    qfrag[0] = *(const short8*)(qbase + (size_t)qi * rowstride + g * 8);
    qfrag[1] = *(const short8*)(qbase + (size_t)qi * rowstride + 32 + g * 8);

    f32x4 oacc[4];
#pragma unroll
    for (int dt = 0; dt < 4; ++dt) oacc[dt] = 0.f;
    float m = -1e30f, l = 0.f;

    for (int s = 0; s < 6; ++s) {
        const int ks0 = q0 - 128 + 32 * s;
        if (ks0 >= 0) {
            const int r = 8 * w + (lane >> 3);      // kv row 0..31
            const int gr = lane & 7;                // dest granule slot
            const size_t krow = (size_t)(2 * (ks0 + r) + p) * rowstride;
            const u16* ksrc = qbase + krow + E_DIM + 8 * (gr ^ (r & 7));  // swizzled src
            const u16* vsrc = qbase + krow + 2 * E_DIM + 8 * gr;          // linear
            GLOAD_LDS16(ksrc, &K_lds[w * 512]);
            GLOAD_LDS16(vsrc, &V_lds[w * 512]);
        }
        __syncthreads();
        const bool active = (ks0 >= 0) && (ks0 <= qmax) && (ks0 + 31 >= qmin - 128);
        if (active) {
            // ---- S^T = K · Q^T (2 k-tiles x 2 d-chunks) ----
            f32x4 st[2];
            st[0] = 0.f; st[1] = 0.f;
#pragma unroll
            for (int t = 0; t < 2; ++t) {
#pragma unroll
                for (int c = 0; c < 2; ++c) {
                    const int kk = t * 16 + q;                  // A-row = key
                    const int gs = (c * 4 + g) ^ (kk & 7);      // un-swizzle
                    short8 kf = *(const short8*)&K_lds[kk * 64 + gs * 8];
                    st[t] = __builtin_amdgcn_mfma_f32_16x16x32_bf16(kf, qfrag[c], st[t], 0, 0, 0);
                }
            }
            // ---- mask + online softmax (per-lane q = lane&15) ----
            float sv[2][4];
            float bm = -3.0e38f;
#pragma unroll
            for (int t = 0; t < 2; ++t)
#pragma unroll
                for (int j = 0; j < 4; ++j) {
                    const int kk = ks0 + t * 16 + 4 * g + j;
                    float x = st[t][j] * 0.125f;
                    const bool ok = (kk <= qs_lane) && (qs_lane - kk <= 128);
                    x = ok ? x : -3.0e38f;
                    sv[t][j] = x;
                    bm = fmaxf(bm, x);
                }
            bm = fmaxf(bm, __shfl_xor(bm, 16));
            bm = fmaxf(bm, __shfl_xor(bm, 32));
            const float mn = fmaxf(m, bm);
            const float sc = __expf(m - mn);
            m = mn;
            float rs = 0.f;
            u32 pk[2][2];
#pragma unroll
            for (int t = 0; t < 2; ++t) {
                const float e0 = __expf(sv[t][0] - mn), e1 = __expf(sv[t][1] - mn);
                const float e2 = __expf(sv[t][2] - mn), e3 = __expf(sv[t][3] - mn);
                rs += (e0 + e1) + (e2 + e3);
                pk[t][0] = (u32)f2bf(e0) | ((u32)f2bf(e1) << 16);
                pk[t][1] = (u32)f2bf(e2) | ((u32)f2bf(e3) << 16);
            }
            rs += __shfl_xor(rs, 16);
            rs += __shfl_xor(rs, 32);
            l = l * sc + rs;
#pragma unroll
            for (int dt = 0; dt < 4; ++dt) oacc[dt] *= sc;
            // ---- P^T (D-layout) -> B-frag via shuffles ----
            union { u32 w4[4]; short8 s8; } bfr;
#pragma unroll
            for (int r = 0; r < 4; ++r) {
                const int src = (((g << 1) + (r >> 1)) & 3) * 16 + q;
                const int w0 = __shfl((int)pk[0][r & 1], src);
                const int w1 = __shfl((int)pk[1][r & 1], src);
                bfr.w4[r] = (g & 2) ? (u32)w1 : (u32)w0;
            }
            // ---- PV: O^T[d][q] += V^T_d · P_q ----
#pragma unroll
            for (int dt = 0; dt < 4; ++dt) {
                union { u16 h8[8]; short8 s8; } vf;
#pragma unroll
                for (int e = 0; e < 8; ++e)
                    vf.h8[e] = V_lds[(8 * g + e) * 64 + dt * 16 + q];
                oacc[dt] = __builtin_amdgcn_mfma_f32_16x16x32_bf16(vf.s8, bfr.s8, oacc[dt], 0, 0, 0);
            }
        }
        __syncthreads();
    }
    const float inv = 1.f / l;
    u16* obase = o + ((size_t)b * L_SEQ + (size_t)qi) * E_DIM + h * HD;
#pragma unroll
    for (int dt = 0; dt < 4; ++dt) {
        u16x4 pkd;
        pkd.x = f2bf(oacc[dt][0] * inv);
        pkd.y = f2bf(oacc[dt][1] * inv);
        pkd.z = f2bf(oacc[dt][2] * inv);
        pkd.w = f2bf(oacc[dt][3] * inv);
        *(u16x4*)(obase + dt * 16 + 4 * g) = pkd;
    }
}

// --------------------------------------------------------------------------------------------
extern "C" void kernel_launch(void* const* d_in, const int* in_sizes, int n_in,
                              void* d_out, int out_size, void* d_ws, size_t ws_size,
                              hipStream_t stream) {
    const float* x    = (const float*)d_in[0];
    const float* ln1g = (const float*)d_in[1];
    const float* ln1b = (const float*)d_in[2];
    const float* qkvw = (const float*)d_in[3];
    const float* qkvb = (const float*)d_in[4];
    const float* outw = (const float*)d_in[5];
    const float* outb = (const float*)d_in[6];
    const float* ln2g = (const float*)d_in[7];
    const float* ln2b = (const float*)d_in[8];
    const float* w1   = (const float*)d_in[9];
    const float* b1   = (const float*)d_in[10];
    const float* w2   = (const float*)d_in[11];
    const float* b2   = (const float*)d_in[12];
    float* outp = (float*)d_out;

    char* ws = (char*)d_ws;
    size_t off = 0;
    auto alloc = [&](size_t bytes) {
        void* p = ws + off;
        off += (bytes + 255) & ~(size_t)255;
        return p;
    };
    u16*   hbuf  = (u16*)  alloc((size_t)BL * E_DIM * 2);
    u16*   qkvB  = (u16*)  alloc((size_t)BL * 3 * E_DIM * 2);
    u16*   obuf  = (u16*)  alloc((size_t)BL * E_DIM * 2);
    float* x2    = (float*)alloc((size_t)BL * E_DIM * 4);
    u16*   h2    = (u16*)  alloc((size_t)BL * E_DIM * 2);
    u16*   g1    = (u16*)  alloc((size_t)BL * HID_DIM * 2);
    u16*   wqkvT = (u16*)  alloc((size_t)3 * E_DIM * E_DIM * 2);
    u16*   woutT = (u16*)  alloc((size_t)E_DIM * E_DIM * 2);
    u16*   w1T   = (u16*)  alloc((size_t)HID_DIM * E_DIM * 2);
    u16*   w2T   = (u16*)  alloc((size_t)E_DIM * HID_DIM * 2);

    wconv_t<<<(E_DIM * 3 * E_DIM + 255) / 256, 256, 0, stream>>>(qkvw, wqkvT, E_DIM, 3 * E_DIM);
    wconv_t<<<(E_DIM * E_DIM + 255) / 256, 256, 0, stream>>>(outw, woutT, E_DIM, E_DIM);
    wconv_t<<<(E_DIM * HID_DIM + 255) / 256, 256, 0, stream>>>(w1, w1T, E_DIM, HID_DIM);
    wconv_t<<<(HID_DIM * E_DIM + 255) / 256, 256, 0, stream>>>(w2, w2T, HID_DIM, E_DIM);

    ln_kernel<<<BL / 4, 256, 0, stream>>>(x, ln1g, ln1b, hbuf);
    gemm_bt<false, false, true><<<dim3((3 * E_DIM) / 128, BL / 128), 256, 0, stream>>>(
        hbuf, wqkvT, qkvb, nullptr, qkvB, BL, 3 * E_DIM, E_DIM);
    attn_mfma<<<dim3(32, 32), 256, 0, stream>>>(qkvB, obuf);
    gemm_bt<true, false, false><<<dim3(E_DIM / 128, BL / 128), 256, 0, stream>>>(
        obuf, woutT, outb, x, x2, BL, E_DIM, E_DIM);
    ln_kernel<<<BL / 4, 256, 0, stream>>>(x2, ln2g, ln2b, h2);
    gemm_bt<false, true, true><<<dim3(HID_DIM / 128, BL / 128), 256, 0, stream>>>(
        h2, w1T, b1, nullptr, g1, BL, HID_DIM, E_DIM);
    gemm_bt<true, false, false><<<dim3(E_DIM / 128, BL / 128), 256, 0, stream>>>(
        g1, w2T, b2, x2, outp, BL, E_DIM, HID_DIM);
}

// Round 3
// 194.198 us; speedup vs baseline: 3.6544x; 1.0269x over previous
//
#include <hip/hip_runtime.h>
#include <math.h>

typedef unsigned short u16;
typedef unsigned int u32;
typedef __attribute__((ext_vector_type(4))) float f32x4;
typedef __attribute__((ext_vector_type(8))) short short8;
typedef __attribute__((ext_vector_type(4))) unsigned short u16x4;

#define B_DIM 2
#define L_SEQ 4096
#define E_DIM 512
#define NH 8
#define HD 64
#define HID_DIM 2048
#define BL (B_DIM * L_SEQ)

__device__ __forceinline__ float bf2f(u16 u) {
    union { u32 i; float f; } v; v.i = ((u32)u) << 16; return v.f;
}
__device__ __forceinline__ u16 f2bf(float f) {
    union { float f; u32 i; } v; v.f = f;
    u32 r = v.i + 0x7fffu + ((v.i >> 16) & 1u);
    return (u16)(r >> 16);
}

#define GLOAD_LDS16(gp, lp) __builtin_amdgcn_global_load_lds( \
    (const __attribute__((address_space(1))) void*)(gp),      \
    (__attribute__((address_space(3))) void*)(lp), 16, 0, 0)

// ---------------- weight convert + transpose via LDS tiles: f32 [Kd][Nd] -> bf16 [Nd][Kd] ----
__global__ __launch_bounds__(256) void wconv_t(const float* __restrict__ in,
                                               u16* __restrict__ out, int Kd, int Nd) {
    __shared__ u16 t[64][72];           // [n][k], pad 8 u16 to break write conflicts
    const int k0 = blockIdx.y * 64, n0 = blockIdx.x * 64;
    const int tid = threadIdx.x;
    const int col4 = tid & 15;          // float4 column (n0 + col4*4 ..+3)
    const int rowb = tid >> 4;          // base row (k), 16 rows per pass
#pragma unroll
    for (int i = 0; i < 4; ++i) {
        const int k = rowb + i * 16;
        const float4 v = *(const float4*)(in + (size_t)(k0 + k) * Nd + n0 + col4 * 4);
        t[col4 * 4 + 0][k] = f2bf(v.x);
        t[col4 * 4 + 1][k] = f2bf(v.y);
        t[col4 * 4 + 2][k] = f2bf(v.z);
        t[col4 * 4 + 3][k] = f2bf(v.w);
    }
    __syncthreads();
    const int n = tid >> 2, ch = tid & 3;   // each thread writes 16 u16 (two 16B stores)
    u16* dst = out + (size_t)(n0 + n) * Kd + k0 + ch * 16;
    *(short8*)(dst) = *(const short8*)&t[n][ch * 16];
    *(short8*)(dst + 8) = *(const short8*)&t[n][ch * 16 + 8];
}

// ---------------- LayerNorm: f32 [rows][512] -> bf16 [rows][512], wave per row ----------------
__global__ __launch_bounds__(256) void ln_kernel(const float* __restrict__ x,
                                                 const float* __restrict__ g,
                                                 const float* __restrict__ b,
                                                 u16* __restrict__ out) {
    const int row = blockIdx.x * 4 + (threadIdx.x >> 6);
    const int lane = threadIdx.x & 63;
    const float4* xr = (const float4*)(x + (size_t)row * E_DIM);
    const float4 v0 = xr[lane];
    const float4 v1 = xr[lane + 64];
    float s  = v0.x + v0.y + v0.z + v0.w + v1.x + v1.y + v1.z + v1.w;
    float s2 = v0.x*v0.x + v0.y*v0.y + v0.z*v0.z + v0.w*v0.w
             + v1.x*v1.x + v1.y*v1.y + v1.z*v1.z + v1.w*v1.w;
#pragma unroll
    for (int off = 32; off > 0; off >>= 1) {
        s  += __shfl_xor(s, off);
        s2 += __shfl_xor(s2, off);
    }
    const float mu = s * (1.f / E_DIM);
    const float rs = rsqrtf(s2 * (1.f / E_DIM) - mu * mu + 1e-5f);
    const float4 g0 = ((const float4*)g)[lane], g1 = ((const float4*)g)[lane + 64];
    const float4 b0 = ((const float4*)b)[lane], b1 = ((const float4*)b)[lane + 64];
    u16x4 o0, o1;
    o0.x = f2bf((v0.x - mu) * rs * g0.x + b0.x);
    o0.y = f2bf((v0.y - mu) * rs * g0.y + b0.y);
    o0.z = f2bf((v0.z - mu) * rs * g0.z + b0.z);
    o0.w = f2bf((v0.w - mu) * rs * g0.w + b0.w);
    o1.x = f2bf((v1.x - mu) * rs * g1.x + b1.x);
    o1.y = f2bf((v1.y - mu) * rs * g1.y + b1.y);
    o1.z = f2bf((v1.z - mu) * rs * g1.z + b1.z);
    o1.w = f2bf((v1.w - mu) * rs * g1.w + b1.w);
    u16x4* orow = (u16x4*)(out + (size_t)row * E_DIM);
    orow[lane] = o0;
    orow[lane + 64] = o1;
}

// ---------------- GEMM: C[M][N] = A[M][K](bf16) @ Bt[N][K](bf16) + bias (+gelu) (+res) -------
// BM=128, BN = 128 or 64, BK=32. 4 waves (2x2). Double-buffered LDS, 2-phase schedule (T3 min).
// LDS layout per operand: [group=16rows][granule=8elem][row] -> fragment read = base + 8*lane
// (contiguous 1KB per wave, conflict-free). Staged by global_load_lds with lane->global
// mapping r=lane&15, g=lane>>4 (dest stays linear, G21).
template<int BN_T, bool RES, bool GELU, bool OUTBF>
__global__ __launch_bounds__(256) void gemm_bt(const u16* __restrict__ A,
                                               const u16* __restrict__ Bt,
                                               const float* __restrict__ bias,
                                               const float* __restrict__ res,
                                               void* __restrict__ Cp,
                                               int M, int N, int K, int nbx) {
    constexpr int NF = BN_T / 32;           // N fragments per wave (4 or 2)
    constexpr int AU = 128 * 32;            // u16 per A buffer
    constexpr int BU = BN_T * 32;           // u16 per B buffer
    __shared__ u16 lds[2][AU + BU];
    const int tid = threadIdx.x;
    const int wave = tid >> 6, lane = tid & 63;
    const int wr = wave >> 1, wc = wave & 1;

    // chunked XCD swizzle (grid % 8 == 0 for all our launches); bx-fastest.
    const int nwg = gridDim.x;
    const int swz = (blockIdx.x & 7) * (nwg >> 3) + (blockIdx.x >> 3);
    const int by = swz / nbx, bx = swz - by * nbx;
    const int bm = by * 128, bn = bx * BN_T;

    f32x4 acc[4][NF];
#pragma unroll
    for (int m = 0; m < 4; ++m)
#pragma unroll
        for (int n = 0; n < NF; ++n) acc[m][n] = 0.f;

    const int sr = lane & 15;               // row within 16-row group
    const int sg = lane >> 4;               // granule (8 u16)
    const u16* gA = A + (size_t)(bm + sr) * K + sg * 8;
    const u16* gB = Bt + (size_t)(bn + sr) * K + sg * 8;

    auto stage = [&](int k0, int buf) {
        u16* la = lds[buf];
        u16* lb = lds[buf] + AU;
#pragma unroll
        for (int h = 0; h < 2; ++h) {
            const int G = wave * 2 + h;
            GLOAD_LDS16(gA + (size_t)G * 16 * K + k0, la + G * 512);
        }
        if (BN_T == 128) {
#pragma unroll
            for (int h = 0; h < 2; ++h) {
                const int G = wave * 2 + h;
                GLOAD_LDS16(gB + (size_t)G * 16 * K + k0, lb + G * 512);
            }
        } else {
            GLOAD_LDS16(gB + (size_t)wave * 16 * K + k0, lb + wave * 512);
        }
    };

    stage(0, 0);
    __syncthreads();
    int cur = 0;
    for (int k0 = 0; k0 < K; k0 += 32) {
        if (k0 + 32 < K) stage(k0 + 32, cur ^ 1);   // prefetch overlaps compute
        const u16* la = lds[cur];
        const u16* lb = lds[cur] + AU;
        short8 af[4], bfr[NF];
#pragma unroll
        for (int m = 0; m < 4; ++m)
            af[m] = *(const short8*)&la[(wr * 4 + m) * 512 + lane * 8];
#pragma unroll
        for (int n = 0; n < NF; ++n)
            bfr[n] = *(const short8*)&lb[(wc * NF + n) * 512 + lane * 8];
#pragma unroll
        for (int m = 0; m < 4; ++m)
#pragma unroll
            for (int n = 0; n < NF; ++n)
                acc[m][n] = __builtin_amdgcn_mfma_f32_16x16x32_bf16(af[m], bfr[n], acc[m][n], 0, 0, 0);
        __syncthreads();                            // drains prefetch + read-done
        cur ^= 1;
    }

    const int ccol = lane & 15;
    const int crow = (lane >> 4) * 4;
#pragma unroll
    for (int n = 0; n < NF; ++n) {
        const int gc = bn + wc * (NF * 16) + n * 16 + ccol;
        const float bi = bias[gc];
#pragma unroll
        for (int m = 0; m < 4; ++m) {
            const int gr0 = bm + wr * 64 + m * 16 + crow;
#pragma unroll
            for (int j = 0; j < 4; ++j) {
                float v = acc[m][n][j] + bi;
                if (GELU) v = 0.5f * v * (1.f + erff(v * 0.70710678118f));
                const size_t idx = (size_t)(gr0 + j) * N + gc;
                if (RES) v += res[idx];
                if (OUTBF) ((u16*)Cp)[idx] = f2bf(v);
                else       ((float*)Cp)[idx] = v;
            }
        }
    }
}

// ---------------- dilated attention via parity split -> dense sliding-window flash attn ------
__global__ __launch_bounds__(256) void attn_mfma(const u16* __restrict__ qkv,
                                                 u16* __restrict__ o) {
    __shared__ u16 K_lds[32 * 64];
    __shared__ u16 V_lds[32 * 64];
    const int tid = threadIdx.x;
    const int w = tid >> 6, lane = tid & 63;
    const int g = lane >> 4, q = lane & 15;
    const int qt = blockIdx.x, bph = blockIdx.y;
    const int b = bph >> 4, p = (bph >> 3) & 1, h = bph & 7;
    const int q0 = qt * 64;

    const size_t rowstride = 3 * E_DIM;
    const u16* qbase = qkv + (size_t)b * L_SEQ * rowstride + h * HD;

    const int qmin = q0 + w * 16, qmax = qmin + 15;
    const int qs_lane = qmin + q;
    const int qi = 2 * qs_lane + p;

    short8 qfrag[2];
    qfrag[0] = *(const short8*)(qbase + (size_t)qi * rowstride + g * 8);
    qfrag[1] = *(const short8*)(qbase + (size_t)qi * rowstride + 32 + g * 8);

    f32x4 oacc[4];
#pragma unroll
    for (int dt = 0; dt < 4; ++dt) oacc[dt] = 0.f;
    float m = -1e30f, l = 0.f;

    for (int s = 0; s < 6; ++s) {
        const int ks0 = q0 - 128 + 32 * s;
        if (ks0 >= 0) {
            const int r = 8 * w + (lane >> 3);
            const int gr = lane & 7;
            const size_t krow = (size_t)(2 * (ks0 + r) + p) * rowstride;
            const u16* ksrc = qbase + krow + E_DIM + 8 * (gr ^ (r & 7));
            const u16* vsrc = qbase + krow + 2 * E_DIM + 8 * gr;
            GLOAD_LDS16(ksrc, &K_lds[w * 512]);
            GLOAD_LDS16(vsrc, &V_lds[w * 512]);
        }
        __syncthreads();
        const bool active = (ks0 >= 0) && (ks0 <= qmax) && (ks0 + 31 >= qmin - 128);
        if (active) {
            f32x4 st[2];
            st[0] = 0.f; st[1] = 0.f;
#pragma unroll
            for (int t = 0; t < 2; ++t) {
#pragma unroll
                for (int c = 0; c < 2; ++c) {
                    const int kk = t * 16 + q;
                    const int gs = (c * 4 + g) ^ (kk & 7);
                    short8 kf = *(const short8*)&K_lds[kk * 64 + gs * 8];
                    st[t] = __builtin_amdgcn_mfma_f32_16x16x32_bf16(kf, qfrag[c], st[t], 0, 0, 0);
                }
            }
            float sv[2][4];
            float bm = -3.0e38f;
#pragma unroll
            for (int t = 0; t < 2; ++t)
#pragma unroll
                for (int j = 0; j < 4; ++j) {
                    const int kk = ks0 + t * 16 + 4 * g + j;
                    float x = st[t][j] * 0.125f;
                    const bool ok = (kk <= qs_lane) && (qs_lane - kk <= 128);
                    x = ok ? x : -3.0e38f;
                    sv[t][j] = x;
                    bm = fmaxf(bm, x);
                }
            bm = fmaxf(bm, __shfl_xor(bm, 16));
            bm = fmaxf(bm, __shfl_xor(bm, 32));
            const float mn = fmaxf(m, bm);
            const float sc = __expf(m - mn);
            m = mn;
            float rs = 0.f;
            u32 pk[2][2];
#pragma unroll
            for (int t = 0; t < 2; ++t) {
                const float e0 = __expf(sv[t][0] - mn), e1 = __expf(sv[t][1] - mn);
                const float e2 = __expf(sv[t][2] - mn), e3 = __expf(sv[t][3] - mn);
                rs += (e0 + e1) + (e2 + e3);
                pk[t][0] = (u32)f2bf(e0) | ((u32)f2bf(e1) << 16);
                pk[t][1] = (u32)f2bf(e2) | ((u32)f2bf(e3) << 16);
            }
            rs += __shfl_xor(rs, 16);
            rs += __shfl_xor(rs, 32);
            l = l * sc + rs;
#pragma unroll
            for (int dt = 0; dt < 4; ++dt) oacc[dt] *= sc;
            union { u32 w4[4]; short8 s8; } bfr;
#pragma unroll
            for (int r = 0; r < 4; ++r) {
                const int src = (((g << 1) + (r >> 1)) & 3) * 16 + q;
                const int w0 = __shfl((int)pk[0][r & 1], src);
                const int w1 = __shfl((int)pk[1][r & 1], src);
                bfr.w4[r] = (g & 2) ? (u32)w1 : (u32)w0;
            }
#pragma unroll
            for (int dt = 0; dt < 4; ++dt) {
                union { u16 h8[8]; short8 s8; } vf;
#pragma unroll
                for (int e = 0; e < 8; ++e)
                    vf.h8[e] = V_lds[(8 * g + e) * 64 + dt * 16 + q];
                oacc[dt] = __builtin_amdgcn_mfma_f32_16x16x32_bf16(vf.s8, bfr.s8, oacc[dt], 0, 0, 0);
            }
        }
        __syncthreads();
    }
    const float inv = 1.f / l;
    u16* obase = o + ((size_t)b * L_SEQ + (size_t)qi) * E_DIM + h * HD;
#pragma unroll
    for (int dt = 0; dt < 4; ++dt) {
        u16x4 pkd;
        pkd.x = f2bf(oacc[dt][0] * inv);
        pkd.y = f2bf(oacc[dt][1] * inv);
        pkd.z = f2bf(oacc[dt][2] * inv);
        pkd.w = f2bf(oacc[dt][3] * inv);
        *(u16x4*)(obase + dt * 16 + 4 * g) = pkd;
    }
}

// --------------------------------------------------------------------------------------------
extern "C" void kernel_launch(void* const* d_in, const int* in_sizes, int n_in,
                              void* d_out, int out_size, void* d_ws, size_t ws_size,
                              hipStream_t stream) {
    const float* x    = (const float*)d_in[0];
    const float* ln1g = (const float*)d_in[1];
    const float* ln1b = (const float*)d_in[2];
    const float* qkvw = (const float*)d_in[3];
    const float* qkvb = (const float*)d_in[4];
    const float* outw = (const float*)d_in[5];
    const float* outb = (const float*)d_in[6];
    const float* ln2g = (const float*)d_in[7];
    const float* ln2b = (const float*)d_in[8];
    const float* w1   = (const float*)d_in[9];
    const float* b1   = (const float*)d_in[10];
    const float* w2   = (const float*)d_in[11];
    const float* b2   = (const float*)d_in[12];
    float* outp = (float*)d_out;

    char* ws = (char*)d_ws;
    size_t off = 0;
    auto alloc = [&](size_t bytes) {
        void* p = ws + off;
        off += (bytes + 255) & ~(size_t)255;
        return p;
    };
    u16*   hbuf  = (u16*)  alloc((size_t)BL * E_DIM * 2);
    u16*   qkvB  = (u16*)  alloc((size_t)BL * 3 * E_DIM * 2);
    u16*   obuf  = (u16*)  alloc((size_t)BL * E_DIM * 2);
    float* x2    = (float*)alloc((size_t)BL * E_DIM * 4);
    u16*   h2    = (u16*)  alloc((size_t)BL * E_DIM * 2);
    u16*   g1    = (u16*)  alloc((size_t)BL * HID_DIM * 2);
    u16*   wqkvT = (u16*)  alloc((size_t)3 * E_DIM * E_DIM * 2);
    u16*   woutT = (u16*)  alloc((size_t)E_DIM * E_DIM * 2);
    u16*   w1T   = (u16*)  alloc((size_t)HID_DIM * E_DIM * 2);
    u16*   w2T   = (u16*)  alloc((size_t)E_DIM * HID_DIM * 2);

    wconv_t<<<dim3((3 * E_DIM) / 64, E_DIM / 64), 256, 0, stream>>>(qkvw, wqkvT, E_DIM, 3 * E_DIM);
    wconv_t<<<dim3(E_DIM / 64, E_DIM / 64), 256, 0, stream>>>(outw, woutT, E_DIM, E_DIM);
    wconv_t<<<dim3(HID_DIM / 64, E_DIM / 64), 256, 0, stream>>>(w1, w1T, E_DIM, HID_DIM);
    wconv_t<<<dim3(E_DIM / 64, HID_DIM / 64), 256, 0, stream>>>(w2, w2T, HID_DIM, E_DIM);

    ln_kernel<<<BL / 4, 256, 0, stream>>>(x, ln1g, ln1b, hbuf);
    gemm_bt<128, false, false, true><<<12 * (BL / 128), 256, 0, stream>>>(
        hbuf, wqkvT, qkvb, nullptr, qkvB, BL, 3 * E_DIM, E_DIM, 12);
    attn_mfma<<<dim3(32, 32), 256, 0, stream>>>(qkvB, obuf);
    gemm_bt<64, true, false, false><<<8 * (BL / 128), 256, 0, stream>>>(
        obuf, woutT, outb, x, x2, BL, E_DIM, E_DIM, 8);
    ln_kernel<<<BL / 4, 256, 0, stream>>>(x2, ln2g, ln2b, h2);
    gemm_bt<128, false, true, true><<<16 * (BL / 128), 256, 0, stream>>>(
        h2, w1T, b1, nullptr, g1, BL, HID_DIM, E_DIM, 16);
    gemm_bt<64, true, false, false><<<8 * (BL / 128), 256, 0, stream>>>(
        g1, w2T, b2, x2, outp, BL, E_DIM, HID_DIM, 8);
}